// Round 3
// baseline (459.744 us; speedup 1.0000x reference)
//
#include <hip/hip_runtime.h>
#include <hip/hip_bf16.h>

// B=1 T=64 W=88 HP=48 F0=53 HL=12 GATES=48 NU=24 NH=4 HD=6 K=25
// All float tensors are float32; condition is int32.
#define NPIX (64*88)          // 5632
#define NSEQ 88
#define TT 64
#define F0 53
#define GATES 48

__device__ __forceinline__ float sigm(float x){ return 1.0f/(1.0f+__expf(-x)); }
__device__ __forceinline__ float tanhfast(float x){ return 2.0f/(1.0f+__expf(-2.0f*x)) - 1.0f; }

__device__ __forceinline__ void load24(const float* __restrict__ src, float* dst){
  const float4* s4 = (const float4*)src;   // rows are 96B-aligned (24 floats * 4B * row)
  #pragma unroll
  for (int u=0; u<6; ++u){
    float4 t = s4[u];
    dst[4*u+0]=t.x; dst[4*u+1]=t.y; dst[4*u+2]=t.z; dst[4*u+3]=t.w;
  }
}

// ---------------- Stage A: build LSTM input -------------------------------
__global__ void k_build_x0(const float* __restrict__ feat, const int* __restrict__ cond,
                           const float* __restrict__ mask, const float* __restrict__ emb,
                           float* __restrict__ x0){
  int tid = blockIdx.x*blockDim.x + threadIdx.x;
  if (tid >= NSEQ*TT*F0) return;
  int f = tid % F0; int r = tid / F0; int t = r % TT; int w = r / TT;
  float v;
  if (f < 48)      v = feat[(t*48 + f)*88 + w];
  else if (f < 52) v = emb[cond[t*88+w]*4 + (f-48)];
  else             v = mask[t*88+w];
  x0[tid] = v;
}

// ---------------- Stage B1: gate precompute gp[((d*88+n)*64+t)*48+j] ------
__global__ void k_gates(const float* __restrict__ xin, const float* __restrict__ wih,
                        const float* __restrict__ bih, const float* __restrict__ bhh,
                        float* __restrict__ gp, int IN){
  int tid = blockIdx.x*blockDim.x + threadIdx.x;
  if (tid >= 2*NSEQ*TT*GATES) return;
  int j = tid % GATES; int r = tid / GATES;
  int t = r % TT; int n = (r/TT) % NSEQ; int d = r / (TT*NSEQ);
  const float* xr = xin + (n*TT + t)*IN;
  const float* wr = wih + (d*GATES + j)*IN;
  float acc = bih[d*GATES+j] + bhh[d*GATES+j];
  for (int f=0; f<IN; ++f) acc += xr[f]*wr[f];
  gp[tid] = acc;
}

// ---------------- Stage B2: recurrence, barrier-free, 1 wave per (dir,seq) -
// h lives in lanes 0..11 registers, broadcast via shfl; no LDS, no barriers.
// mode 0: yout[(n*64+t)*24 + d*12+j]; mode 1: yout[(t*88+n)*24 + d*12+j]
__global__ __launch_bounds__(64) void k_lstm_rec(const float* __restrict__ gp,
                          const float* __restrict__ whh,
                          float* __restrict__ yout, int mode){
  int b = blockIdx.x; int d = b / NSEQ; int n = b % NSEQ;
  int lane = threadIdx.x;
  int jl = lane < GATES ? lane : 0;
  float w[12];
  #pragma unroll
  for (int m=0;m<12;++m) w[m] = whh[(d*GATES+jl)*12+m];
  const float* gpb = gp + (size_t)(d*NSEQ + n)*TT*GATES;
  float hval = 0.f, cval = 0.f;
  int gl = lane < 12 ? lane : 0;
  int t0 = d ? (TT-1) : 0;
  float gnext = gpb[t0*GATES + jl];
  for (int s=0;s<TT;++s){
    int t = d ? (TT-1-s) : s;
    float g = gnext;
    if (s+1 < TT){
      int tn = d ? (TT-2-s) : (s+1);
      gnext = gpb[tn*GATES + jl];     // prefetch next step while this one computes
    }
    #pragma unroll
    for (int m=0;m<12;++m) g += __shfl(hval, m) * w[m];
    float xi = __shfl(g, gl);
    float xf = __shfl(g, gl+12);
    float xg = __shfl(g, gl+24);
    float xo = __shfl(g, gl+36);
    float cn = sigm(xf)*cval + sigm(xi)*tanhfast(xg);
    float hn = sigm(xo)*tanhfast(cn);
    cval = cn; hval = hn;
    if (lane < 12){
      int off = d*12 + lane;
      if (mode==0) yout[(n*TT+t)*24 + off] = hn;
      else         yout[(t*88+n)*24 + off] = hn;
    }
  }
}

// ---------------- Stage C1: qkv projection --------------------------------
__global__ void k_qkv(const float* __restrict__ xin, const float* __restrict__ qkv_w,
                      const float* __restrict__ qkv_b, float* __restrict__ q,
                      float* __restrict__ k, float* __restrict__ v){
  int tid = blockIdx.x*blockDim.x + threadIdx.x;
  if (tid >= NPIX*72) return;
  int g = tid % 72; int r = tid / 72;
  const float* xr = xin + r*24;
  const float* wr = qkv_w + g*24;
  float acc = qkv_b[g];
  #pragma unroll
  for (int cidx=0; cidx<24; ++cidx) acc += xr[cidx]*wr[cidx];
  int s = g/24, rem = g - s*24;
  if (s==0)      q[r*24+rem] = acc*0.4082482904638631f;   // 1/sqrt(HD)
  else if (s==1) k[r*24+rem] = acc;
  else           v[r*24+rem] = acc;
}

// ---------------- Stage C2: attention, 1 wave per PIXEL, all 4 heads ------
__global__ __launch_bounds__(64) void k_attn(const float* __restrict__ q,
                      const float* __restrict__ kk, const float* __restrict__ vv,
                      const float* __restrict__ rpb, float* __restrict__ ao){
  int p = blockIdx.x;
  int i = p / 88, j = p - i*88;
  int si = min(max(i-12,0),39), sj = min(max(j-12,0),63);
  int lane = threadIdx.x;
  float qv[24];
  load24(q + p*24, qv);

  float pr[10][4];
  int   voff[10];
  float mx[4] = {-1e30f,-1e30f,-1e30f,-1e30f};
  #pragma unroll
  for (int it=0; it<10; ++it){
    int nb = lane + it*64;
    bool valid = nb < 625;
    int nbc = valid ? nb : 624;
    int a = nbc/25, cc = nbc - a*25;
    int gi = si + a, gj = sj + cc;
    int off = (gi*88+gj)*24;
    voff[it] = off;
    float kr[24];
    load24(kk + off, kr);
    const float* rb = rpb + (gi - i + 24)*49 + (gj - j + 24);
    #pragma unroll
    for (int h=0; h<4; ++h){
      float lg = rb[h*2401];
      #pragma unroll
      for (int d=0; d<6; ++d) lg += qv[h*6+d]*kr[h*6+d];
      lg = valid ? lg : -1e30f;
      pr[it][h] = lg;
      mx[h] = fmaxf(mx[h], lg);
    }
  }
  #pragma unroll
  for (int h=0; h<4; ++h)
    #pragma unroll
    for (int off=32; off; off>>=1) mx[h] = fmaxf(mx[h], __shfl_xor(mx[h], off));
  float sm[4] = {0,0,0,0};
  #pragma unroll
  for (int it=0; it<10; ++it)
    #pragma unroll
    for (int h=0; h<4; ++h){
      float e = __expf(pr[it][h] - mx[h]);   // invalid -> exp(-huge) = 0
      pr[it][h] = e; sm[h] += e;
    }
  #pragma unroll
  for (int h=0; h<4; ++h)
    #pragma unroll
    for (int off=32; off; off>>=1) sm[h] += __shfl_xor(sm[h], off);

  float acc[24];
  #pragma unroll
  for (int u=0; u<24; ++u) acc[u] = 0.f;
  #pragma unroll
  for (int it=0; it<10; ++it){
    float vr[24];
    load24(vv + voff[it], vr);
    #pragma unroll
    for (int h=0; h<4; ++h){
      float pe = pr[it][h];
      #pragma unroll
      for (int d=0; d<6; ++d) acc[h*6+d] += pe*vr[h*6+d];
    }
  }
  #pragma unroll
  for (int u=0; u<24; ++u)
    #pragma unroll
    for (int off=32; off; off>>=1) acc[u] += __shfl_xor(acc[u], off);

  if (lane == 0){
    float inv[4];
    #pragma unroll
    for (int h=0; h<4; ++h) inv[h] = 1.f/sm[h];
    float4* o4 = (float4*)(ao + p*24);
    #pragma unroll
    for (int u=0; u<6; ++u){
      float4 t;
      t.x = acc[4*u+0]*inv[(4*u+0)/6];
      t.y = acc[4*u+1]*inv[(4*u+1)/6];
      t.z = acc[4*u+2]*inv[(4*u+2)/6];
      t.w = acc[4*u+3]*inv[(4*u+3)/6];
      o4[u] = t;
    }
  }
}

// ---------------- Fused: proj then qkv (middle of the two NATTEN layers) ---
__global__ __launch_bounds__(64) void k_proj_qkv(const float* __restrict__ ain,
                      const float* __restrict__ pw, const float* __restrict__ pb,
                      const float* __restrict__ qkv_w, const float* __restrict__ qkv_b,
                      float* __restrict__ q, float* __restrict__ k, float* __restrict__ v){
  int p = blockIdx.x; int tid = threadIdx.x;
  __shared__ float arow[24];
  __shared__ float xrow[24];
  if (tid < 24) arow[tid] = ain[p*24+tid];
  __syncthreads();
  if (tid < 24){
    float acc = pb[tid];
    const float* wr = pw + tid*24;
    #pragma unroll
    for (int c=0;c<24;++c) acc += arow[c]*wr[c];
    xrow[tid] = acc;
  }
  __syncthreads();
  for (int g = tid; g < 72; g += 64){
    float acc = qkv_b[g];
    const float* wr = qkv_w + g*24;
    #pragma unroll
    for (int c=0;c<24;++c) acc += xrow[c]*wr[c];
    int s = g/24, rem = g - s*24;
    if (s==0)      q[p*24+rem] = acc*0.4082482904638631f;
    else if (s==1) k[p*24+rem] = acc;
    else           v[p*24+rem] = acc;
  }
}

// ---------------- Fused: proj then final 24->5 head ------------------------
__global__ __launch_bounds__(64) void k_proj_out(const float* __restrict__ ain,
                      const float* __restrict__ pw, const float* __restrict__ pb,
                      const float* __restrict__ ow, const float* __restrict__ ob,
                      float* __restrict__ out){
  int p = blockIdx.x; int tid = threadIdx.x;
  __shared__ float arow[24];
  __shared__ float xrow[24];
  if (tid < 24) arow[tid] = ain[p*24+tid];
  __syncthreads();
  if (tid < 24){
    float acc = pb[tid];
    const float* wr = pw + tid*24;
    #pragma unroll
    for (int c=0;c<24;++c) acc += arow[c]*wr[c];
    xrow[tid] = acc;
  }
  __syncthreads();
  if (tid < 5){
    float acc = ob[tid];
    const float* wr = ow + tid*24;
    #pragma unroll
    for (int c=0;c<24;++c) acc += xrow[c]*wr[c];
    out[p*5+tid] = acc;
  }
}

extern "C" void kernel_launch(void* const* d_in, const int* in_sizes, int n_in,
                              void* d_out, int out_size, void* d_ws, size_t ws_size,
                              hipStream_t stream) {
  const float* feat    = (const float*)d_in[0];
  const int*   cond    = (const int*)  d_in[1];
  const float* mask    = (const float*)d_in[2];
  const float* emb     = (const float*)d_in[3];
  const float* w_ih_l0 = (const float*)d_in[4];
  const float* w_hh_l0 = (const float*)d_in[5];
  const float* b_ih_l0 = (const float*)d_in[6];
  const float* b_hh_l0 = (const float*)d_in[7];
  const float* w_ih_l1 = (const float*)d_in[8];
  const float* w_hh_l1 = (const float*)d_in[9];
  const float* b_ih_l1 = (const float*)d_in[10];
  const float* b_hh_l1 = (const float*)d_in[11];
  const float* qkv_w   = (const float*)d_in[12];
  const float* qkv_b   = (const float*)d_in[13];
  const float* rpb     = (const float*)d_in[14];
  const float* proj_w  = (const float*)d_in[15];
  const float* proj_b  = (const float*)d_in[16];
  const float* out_w   = (const float*)d_in[17];
  const float* out_b   = (const float*)d_in[18];
  float* out = (float*)d_out;

  float* ws = (float*)d_ws;
  float* X0 = ws;               // 298496
  float* GP = X0 + 298496;      // 540672
  float* Y0 = GP + 540672;      // 135168
  float* XA = Y0 + 135168;      // 135168
  float* Q  = XA + 135168;      // 135168
  float* Kb = Q  + 135168;      // 135168
  float* Vb = Kb + 135168;      // 135168
  float* AO = Vb + 135168;      // 135168

  k_build_x0<<<(NSEQ*TT*F0 + 255)/256, 256, 0, stream>>>(feat, cond, mask, emb, X0);

  k_gates<<<(2*NSEQ*TT*GATES + 255)/256, 256, 0, stream>>>(X0, w_ih_l0, b_ih_l0, b_hh_l0, GP, F0);
  k_lstm_rec<<<2*NSEQ, 64, 0, stream>>>(GP, w_hh_l0, Y0, 0);
  k_gates<<<(2*NSEQ*TT*GATES + 255)/256, 256, 0, stream>>>(Y0, w_ih_l1, b_ih_l1, b_hh_l1, GP, 24);
  k_lstm_rec<<<2*NSEQ, 64, 0, stream>>>(GP, w_hh_l1, XA, 1);

  k_qkv     <<<(NPIX*72 + 255)/256, 256, 0, stream>>>(XA, qkv_w, qkv_b, Q, Kb, Vb);
  k_attn    <<<NPIX, 64, 0, stream>>>(Q, Kb, Vb, rpb, AO);
  k_proj_qkv<<<NPIX, 64, 0, stream>>>(AO, proj_w, proj_b, qkv_w, qkv_b, Q, Kb, Vb);
  k_attn    <<<NPIX, 64, 0, stream>>>(Q, Kb, Vb, rpb, AO);
  k_proj_out<<<NPIX, 64, 0, stream>>>(AO, proj_w, proj_b, out_w, out_b, out);
}

// Round 4
// 313.260 us; speedup vs baseline: 1.4676x; 1.4676x over previous
//
#include <hip/hip_runtime.h>
#include <hip/hip_bf16.h>

// B=1 T=64 W=88 HP=48 F0=53 HL=12 GATES=48 NU=24 NH=4 HD=6 K=25
// All float tensors are float32; condition is int32.
#define NPIX (64*88)          // 5632
#define NSEQ 88
#define TT 64
#define F0 53
#define GATES 48

__device__ __forceinline__ float sigm(float x){ return 1.0f/(1.0f+__expf(-x)); }
__device__ __forceinline__ float tanhfast(float x){ return 2.0f/(1.0f+__expf(-2.0f*x)) - 1.0f; }

// ---------------- Stage A: build LSTM input -------------------------------
__global__ void k_build_x0(const float* __restrict__ feat, const int* __restrict__ cond,
                           const float* __restrict__ mask, const float* __restrict__ emb,
                           float* __restrict__ x0){
  int tid = blockIdx.x*blockDim.x + threadIdx.x;
  if (tid >= NSEQ*TT*F0) return;
  int f = tid % F0; int r = tid / F0; int t = r % TT; int w = r / TT;
  float v;
  if (f < 48)      v = feat[(t*48 + f)*88 + w];
  else if (f < 52) v = emb[cond[t*88+w]*4 + (f-48)];
  else             v = mask[t*88+w];
  x0[tid] = v;
}

// ---------------- Stage B1: gate precompute gp[((d*88+n)*64+t)*48+j] ------
__global__ void k_gates(const float* __restrict__ xin, const float* __restrict__ wih,
                        const float* __restrict__ bih, const float* __restrict__ bhh,
                        float* __restrict__ gp, int IN){
  int tid = blockIdx.x*blockDim.x + threadIdx.x;
  if (tid >= 2*NSEQ*TT*GATES) return;
  int j = tid % GATES; int r = tid / GATES;
  int t = r % TT; int n = (r/TT) % NSEQ; int d = r / (TT*NSEQ);
  const float* xr = xin + (n*TT + t)*IN;
  const float* wr = wih + (d*GATES + j)*IN;
  float acc = bih[d*GATES+j] + bhh[d*GATES+j];
  for (int f=0; f<IN; ++f) acc += xr[f]*wr[f];
  gp[tid] = acc;
}

// ---------------- Stage B2: recurrence, barrier-free, 1 wave per (dir,seq) -
__global__ __launch_bounds__(64) void k_lstm_rec(const float* __restrict__ gp,
                          const float* __restrict__ whh,
                          float* __restrict__ yout, int mode){
  int b = blockIdx.x; int d = b / NSEQ; int n = b % NSEQ;
  int lane = threadIdx.x;
  int jl = lane < GATES ? lane : 0;
  float w[12];
  #pragma unroll
  for (int m=0;m<12;++m) w[m] = whh[(d*GATES+jl)*12+m];
  const float* gpb = gp + (size_t)(d*NSEQ + n)*TT*GATES;
  float hval = 0.f, cval = 0.f;
  int gl = lane < 12 ? lane : 0;
  int t0 = d ? (TT-1) : 0;
  float gnext = gpb[t0*GATES + jl];
  for (int s=0;s<TT;++s){
    int t = d ? (TT-1-s) : s;
    float g = gnext;
    if (s+1 < TT){
      int tn = d ? (TT-2-s) : (s+1);
      gnext = gpb[tn*GATES + jl];
    }
    #pragma unroll
    for (int m=0;m<12;++m) g += __shfl(hval, m) * w[m];
    float xi = __shfl(g, gl);
    float xf = __shfl(g, gl+12);
    float xg = __shfl(g, gl+24);
    float xo = __shfl(g, gl+36);
    float cn = sigm(xf)*cval + sigm(xi)*tanhfast(xg);
    float hn = sigm(xo)*tanhfast(cn);
    cval = cn; hval = hn;
    if (lane < 12){
      int off = d*12 + lane;
      if (mode==0) yout[(n*TT+t)*24 + off] = hn;
      else         yout[(t*88+n)*24 + off] = hn;
    }
  }
}

// ---------------- Stage C1: qkv projection (K/V per-head, rows padded to 8) -
// kh/vh layout: [h][pix][8], floats 6,7 zeroed.
__global__ void k_qkv(const float* __restrict__ xin, const float* __restrict__ qkv_w,
                      const float* __restrict__ qkv_b, float* __restrict__ q,
                      float* __restrict__ kh, float* __restrict__ vh){
  int tid = blockIdx.x*blockDim.x + threadIdx.x;
  if (tid >= NPIX*72) return;
  int g = tid % 72; int r = tid / 72;
  const float* xr = xin + r*24;
  const float* wr = qkv_w + g*24;
  float acc = qkv_b[g];
  #pragma unroll
  for (int cidx=0; cidx<24; ++cidx) acc += xr[cidx]*wr[cidx];
  int s = g/24, rem = g - s*24;
  if (s==0) q[r*24+rem] = acc*0.4082482904638631f;   // 1/sqrt(HD)
  else {
    int hh = rem/6, pos = rem - hh*6;
    float* dst = (s==1) ? kh : vh;
    size_t base = ((size_t)hh*NPIX + r)*8;
    dst[base + pos] = acc;
    if (pos < 2) dst[base + 6 + pos] = 0.f;
  }
}

// ---------------- Stage C2: attention, 1 wave per (pixel,head) ------------
__global__ __launch_bounds__(64) void k_attn(const float* __restrict__ q,
                      const float* __restrict__ kh, const float* __restrict__ vh,
                      const float* __restrict__ rpb, float* __restrict__ ao){
  int b = blockIdx.x; int h = b & 3; int p = b >> 2;
  int i = p / 88, j = p - i*88;
  int si = min(max(i-12,0),39), sj = min(max(j-12,0),63);
  int lane = threadIdx.x;
  float qv[6];
  #pragma unroll
  for (int d=0; d<6; ++d) qv[d] = q[p*24 + h*6 + d];
  const float* kb = kh + (size_t)h*NPIX*8;
  const float* vb = vh + (size_t)h*NPIX*8;
  float lgv[10]; int roff[10];
  float lmax = -1e30f;
  #pragma unroll
  for (int it=0; it<10; ++it){
    int nb = lane + it*64;
    bool valid = nb < 625;
    int nbc = valid ? nb : 624;
    int a = nbc/25, cc = nbc - a*25;
    int gi = si + a, gj = sj + cc;
    int off = (gi*88+gj)*8;
    roff[it] = off;
    float4 k0 = *(const float4*)(kb + off);
    float4 k1 = *(const float4*)(kb + off + 4);
    float lg = qv[0]*k0.x+qv[1]*k0.y+qv[2]*k0.z+qv[3]*k0.w+qv[4]*k1.x+qv[5]*k1.y;
    lg += rpb[(h*49 + (gi - i + 24))*49 + (gj - j + 24)];
    lg = valid ? lg : -1e30f;
    lgv[it] = lg;
    lmax = fmaxf(lmax, lg);
  }
  #pragma unroll
  for (int off=32; off; off>>=1) lmax = fmaxf(lmax, __shfl_xor(lmax, off));
  float lsum = 0.f;
  #pragma unroll
  for (int it=0; it<10; ++it){
    float pe = __expf(lgv[it]-lmax);   // invalid lanes -> exp(-huge)=0
    lgv[it] = pe; lsum += pe;
  }
  #pragma unroll
  for (int off=32; off; off>>=1) lsum += __shfl_xor(lsum, off);
  float acc[6] = {0,0,0,0,0,0};
  #pragma unroll
  for (int it=0; it<10; ++it){
    float4 v0 = *(const float4*)(vb + roff[it]);
    float4 v1 = *(const float4*)(vb + roff[it] + 4);
    float pe = lgv[it];
    acc[0] += pe*v0.x; acc[1] += pe*v0.y; acc[2] += pe*v0.z;
    acc[3] += pe*v0.w; acc[4] += pe*v1.x; acc[5] += pe*v1.y;
  }
  #pragma unroll
  for (int d=0; d<6; ++d){
    #pragma unroll
    for (int off=32; off; off>>=1) acc[d] += __shfl_xor(acc[d], off);
  }
  if (lane == 0){
    float inv = 1.f/lsum;
    #pragma unroll
    for (int d=0; d<6; ++d) ao[p*24 + h*6 + d] = acc[d]*inv;
  }
}

// ---------------- Fused: proj then qkv (between the two NATTEN layers) -----
__global__ __launch_bounds__(64) void k_proj_qkv(const float* __restrict__ ain,
                      const float* __restrict__ pw, const float* __restrict__ pb,
                      const float* __restrict__ qkv_w, const float* __restrict__ qkv_b,
                      float* __restrict__ q, float* __restrict__ kh, float* __restrict__ vh){
  int p = blockIdx.x; int tid = threadIdx.x;
  __shared__ float arow[24];
  __shared__ float xrow[24];
  if (tid < 24) arow[tid] = ain[p*24+tid];
  __syncthreads();
  if (tid < 24){
    float acc = pb[tid];
    const float* wr = pw + tid*24;
    #pragma unroll
    for (int c=0;c<24;++c) acc += arow[c]*wr[c];
    xrow[tid] = acc;
  }
  __syncthreads();
  for (int g = tid; g < 72; g += 64){
    float acc = qkv_b[g];
    const float* wr = qkv_w + g*24;
    #pragma unroll
    for (int c=0;c<24;++c) acc += xrow[c]*wr[c];
    int s = g/24, rem = g - s*24;
    if (s==0) q[p*24+rem] = acc*0.4082482904638631f;
    else {
      int hh = rem/6, pos = rem - hh*6;
      float* dst = (s==1) ? kh : vh;
      size_t base = ((size_t)hh*NPIX + p)*8;
      dst[base + pos] = acc;
      if (pos < 2) dst[base + 6 + pos] = 0.f;
    }
  }
}

// ---------------- Fused: proj then final 24->5 head ------------------------
__global__ __launch_bounds__(64) void k_proj_out(const float* __restrict__ ain,
                      const float* __restrict__ pw, const float* __restrict__ pb,
                      const float* __restrict__ ow, const float* __restrict__ ob,
                      float* __restrict__ out){
  int p = blockIdx.x; int tid = threadIdx.x;
  __shared__ float arow[24];
  __shared__ float xrow[24];
  if (tid < 24) arow[tid] = ain[p*24+tid];
  __syncthreads();
  if (tid < 24){
    float acc = pb[tid];
    const float* wr = pw + tid*24;
    #pragma unroll
    for (int c=0;c<24;++c) acc += arow[c]*wr[c];
    xrow[tid] = acc;
  }
  __syncthreads();
  if (tid < 5){
    float acc = ob[tid];
    const float* wr = ow + tid*24;
    #pragma unroll
    for (int c=0;c<24;++c) acc += xrow[c]*wr[c];
    out[p*5+tid] = acc;
  }
}

extern "C" void kernel_launch(void* const* d_in, const int* in_sizes, int n_in,
                              void* d_out, int out_size, void* d_ws, size_t ws_size,
                              hipStream_t stream) {
  const float* feat    = (const float*)d_in[0];
  const int*   cond    = (const int*)  d_in[1];
  const float* mask    = (const float*)d_in[2];
  const float* emb     = (const float*)d_in[3];
  const float* w_ih_l0 = (const float*)d_in[4];
  const float* w_hh_l0 = (const float*)d_in[5];
  const float* b_ih_l0 = (const float*)d_in[6];
  const float* b_hh_l0 = (const float*)d_in[7];
  const float* w_ih_l1 = (const float*)d_in[8];
  const float* w_hh_l1 = (const float*)d_in[9];
  const float* b_ih_l1 = (const float*)d_in[10];
  const float* b_hh_l1 = (const float*)d_in[11];
  const float* qkv_w   = (const float*)d_in[12];
  const float* qkv_b   = (const float*)d_in[13];
  const float* rpb     = (const float*)d_in[14];
  const float* proj_w  = (const float*)d_in[15];
  const float* proj_b  = (const float*)d_in[16];
  const float* out_w   = (const float*)d_in[17];
  const float* out_b   = (const float*)d_in[18];
  float* out = (float*)d_out;

  float* ws = (float*)d_ws;
  float* X0 = ws;               // 298496
  float* GP = X0 + 298496;      // 540672
  float* Y0 = GP + 540672;      // 135168
  float* XA = Y0 + 135168;      // 135168
  float* Q  = XA + 135168;      // 135168
  float* KH = Q  + 135168;      // 4*5632*8 = 180224
  float* VH = KH + 180224;      // 180224
  float* AO = VH + 180224;      // 135168   (total ~1.74M floats = 7.0 MB)

  k_build_x0<<<(NSEQ*TT*F0 + 255)/256, 256, 0, stream>>>(feat, cond, mask, emb, X0);

  k_gates<<<(2*NSEQ*TT*GATES + 255)/256, 256, 0, stream>>>(X0, w_ih_l0, b_ih_l0, b_hh_l0, GP, F0);
  k_lstm_rec<<<2*NSEQ, 64, 0, stream>>>(GP, w_hh_l0, Y0, 0);
  k_gates<<<(2*NSEQ*TT*GATES + 255)/256, 256, 0, stream>>>(Y0, w_ih_l1, b_ih_l1, b_hh_l1, GP, 24);
  k_lstm_rec<<<2*NSEQ, 64, 0, stream>>>(GP, w_hh_l1, XA, 1);

  k_qkv     <<<(NPIX*72 + 255)/256, 256, 0, stream>>>(XA, qkv_w, qkv_b, Q, KH, VH);
  k_attn    <<<NPIX*4, 64, 0, stream>>>(Q, KH, VH, rpb, AO);
  k_proj_qkv<<<NPIX, 64, 0, stream>>>(AO, proj_w, proj_b, qkv_w, qkv_b, Q, KH, VH);
  k_attn    <<<NPIX*4, 64, 0, stream>>>(Q, KH, VH, rpb, AO);
  k_proj_out<<<NPIX, 64, 0, stream>>>(AO, proj_w, proj_b, out_w, out_b, out);
}